// Round 10
// baseline (42.597 us; speedup 1.0000x reference)
//
#include <hip/hip_runtime.h>
#include <math.h>

// FusedAttentionWithRPB round 10: 32x32 MFMA, swapped operands (T12 structure).
//  - 128-thread blocks, 2 waves x 32 q-rows; 4 blocks/CU (LDS ~33 KB)
//  - QK swapped: lane holds P[key][q=lane&31] -> lane-local softmax (1 shfl)
//  - PV swapped: O^T = mfma(Vt, P); P B-frags built in-register (no Ps LDS)
//  - KA async gl16 double-buffer; V frags + kz global-direct; 1 barrier/step

constexpr int Bc = 4, Hc = 8, Sc = 1024, Dc = 64;

constexpr size_t KA_BYTES   = (size_t)32 * 1024 * 256;            // 8 MB
constexpr size_t VT_BYTES   = (size_t)32 * 16 * 64 * 128;         // 4 MB
constexpr size_t PART_OFF   = KA_BYTES + VT_BYTES;
constexpr size_t PART_BYTES = (size_t)32 * 12 * 3 * 64 * 68 * sizeof(float);
constexpr size_t WS_SPLIT   = PART_OFF + PART_BYTES;

typedef __attribute__((ext_vector_type(8)))  short bf16x8;
typedef __attribute__((ext_vector_type(16))) float f32x16;

// chunk tables: cid -> (qi, ktb, kte, part), heavy-first (LPT)
__device__ __constant__ signed char CQI[32] =
  {15,11,11,10,15,15,14,14,14,13,13,12,10, 9, 9, 8,13,12,12, 8, 7, 7, 6, 3, 6, 5, 5, 4, 2, 4, 1, 0};
__device__ __constant__ signed char CKTB[32] =
  {10, 0, 6, 5, 0, 5, 0, 5,10, 4, 9, 8, 0, 0, 5, 4, 0, 0, 4, 0, 0, 4, 3, 0, 0, 0, 3, 2, 0, 0, 0, 0};
__device__ __constant__ signed char CKTE[32] =
  {16, 6,12,11, 5,10, 5,10,15, 9,14,13, 5, 5,10, 9, 4, 4, 8, 4, 4, 8, 7, 4, 3, 3, 6, 5, 3, 2, 2, 1};
__device__ __constant__ signed char CPT[32] =
  { 2, 0, 1, 1, 0, 1, 0, 1, 2, 1, 2, 2, 0, 0, 1, 1, 0, 0, 1, 0, 0, 1, 1, 0, 0, 0, 1, 1, 0, 0, 0, 0};

__device__ __forceinline__ unsigned short f2bf(float f) {
  union { float f; unsigned u; } x; x.f = f;
  unsigned r = x.u + 0x7FFFu + ((x.u >> 16) & 1u);
  return (unsigned short)(r >> 16);
}
__device__ __forceinline__ unsigned pack2(float a, float b) {
  return (unsigned)f2bf(a) | ((unsigned)f2bf(b) << 16);
}
__device__ __forceinline__ bf16x8 pack8(float4 a, float4 b) {
  bf16x8 r;
  r[0] = (short)f2bf(a.x); r[1] = (short)f2bf(a.y);
  r[2] = (short)f2bf(a.z); r[3] = (short)f2bf(a.w);
  r[4] = (short)f2bf(b.x); r[5] = (short)f2bf(b.y);
  r[6] = (short)f2bf(b.z); r[7] = (short)f2bf(b.w);
  return r;
}
__device__ __forceinline__ float4 sc4(float4 a, float s) {
  return make_float4(a.x*s, a.y*s, a.z*s, a.w*s);
}
__device__ __forceinline__ void gl16(const void* g, void* l) {
  __builtin_amdgcn_global_load_lds(
      (const __attribute__((address_space(1))) void*)g,
      (__attribute__((address_space(3))) void*)l, 16, 0, 0);
}

// ---- fused pre-pass (unchanged layout): KA rows 256B (slots XOR key&7),
// Vt rows 128B per (bh,tile,d) (slots XOR d&7).
__global__ __launch_bounds__(256) void prep(
    const float* __restrict__ kg, const float* __restrict__ vg,
    const int* __restrict__ px, const int* __restrict__ py,
    const float* __restrict__ bx, const float* __restrict__ by,
    unsigned short* __restrict__ wsKA, unsigned short* __restrict__ wsVt)
{
  const int t = threadIdx.x;
  if (blockIdx.x < 512) {
    const int g = blockIdx.x * 64 + (t >> 2);
    const int p = t & 3;
    const int bh = g >> 10, key = g & 1023;
    const int b = bh >> 3, h = bh & 7;
    const float* ksrc = kg + ((size_t)bh * Sc + key) * Dc + p * 16;
    float4 f0 = ((const float4*)ksrc)[0], f1 = ((const float4*)ksrc)[1];
    float4 f2 = ((const float4*)ksrc)[2], f3 = ((const float4*)ksrc)[3];
    unsigned short* rowp = wsKA + (size_t)g * 128;
    const int rx = key & 7;
    *(bf16x8*)(rowp + (((2*p)   ^ rx) << 3)) = pack8(f0, f1);
    *(bf16x8*)(rowp + (((2*p+1) ^ rx) << 3)) = pack8(f2, f3);
    const int kx = px[b * Sc + key], ky = py[b * Sc + key];
    bf16x8 xv, yv;
    #pragma unroll
    for (int m = 0; m < 8; ++m) {
      int ix = 8*p + m - kx; ix = ix < -30 ? -30 : (ix > 30 ? 30 : ix);
      int iy = 8*p + m - ky; iy = iy < -30 ? -30 : (iy > 30 ? 30 : iy);
      xv[m] = (short)f2bf(bx[(ix + 30) * Hc + h]);
      yv[m] = (short)f2bf(by[(iy + 30) * Hc + h]);
    }
    *(bf16x8*)(rowp + (((8  + p) ^ rx) << 3)) = xv;
    *(bf16x8*)(rowp + (((12 + p) ^ rx) << 3)) = yv;
  } else {
    const int bid = blockIdx.x - 512;
    const int bh = bid >> 4, tt = bid & 15;
    const int d = t & 63, cg = t >> 6;
    unsigned short* rowp = wsVt + (((size_t)bh * 16 + tt) * 64 + d) * 64;
    const float* vbase = vg + ((size_t)bh * Sc + tt * 64) * Dc + d;
    #pragma unroll
    for (int cc = 0; cc < 2; ++cc) {
      const int c = 2 * cg + cc;
      bf16x8 vv;
      #pragma unroll
      for (int jj = 0; jj < 8; ++jj)
        vv[jj] = (short)f2bf(vbase[(8*c + jj) * Dc]);
      *(bf16x8*)(rowp + ((c ^ (d & 7)) << 3)) = vv;
    }
  }
}

// ---- main kernel: 128 threads, 2 waves
__global__ __launch_bounds__(128, 2) void attn_rpb_mfma9(
    const float* __restrict__ qg,
    const int* __restrict__ px, const int* __restrict__ py, const int* __restrict__ pz,
    const float* __restrict__ bz,
    const unsigned short* __restrict__ wsKA, const unsigned short* __restrict__ wsVt,
    float* __restrict__ outg, float* __restrict__ wsPart, int mode)
{
  int qi, ktb, kte, part, np, bh;
  {
    const int j = blockIdx.x;
    if (mode == 0) {
      const int idx = j & 255; bh = idx >> 3; const int r3 = idx & 7;
      qi = (j < 256) ? (15 - r3) : r3;
      ktb = 0; kte = qi + 1; part = 0; np = 1;
    } else {
      bh = j & 31;
      const int cid = j >> 5;
      qi = CQI[cid]; ktb = CKTB[cid]; kte = CKTE[cid]; part = CPT[cid];
      np = (qi < 4) ? 1 : ((qi < 12) ? 2 : 3);
    }
  }
  const int h = bh & 7, b = bh >> 3;

  __shared__ unsigned short KAb[2][64 * 128];   // 32 KB, async dbuf
  __shared__ float BZ2[256];

  const int t   = threadIdx.x;
  const int w2  = t >> 6;        // wave 0..1 -> q rows [32w2, 32w2+32)
  const int l   = t & 63;
  const int q32 = l & 31;        // q-local (C/D col)
  const int hi  = l >> 5;        // k-half selector for A/B frags
  const size_t bhOff = (size_t)bh * Sc;
  const int q0 = qi * 64;
  const int myq = q0 + 32*w2 + q32;

  const char* kaSrc = (const char*)wsKA;
  const char* vtSrc = (const char*)wsVt;

  // ---- prologue: stage KA[ktb]; BZ2 table; Q/one-hot B-frags -> regs
  {
    const char* srcK = kaSrc + ((size_t)(bh*1024 + ktb*64)) * 256 + t*16;
    #pragma unroll
    for (int r8 = 0; r8 < 8; ++r8)
      gl16(srcK + r8*2048, (char*)KAb[0] + r8*2048 + w2*1024);
  }
  #pragma unroll
  for (int e = t; e < 256; e += 128) {
    int dzz = (e >> 4) - (e & 15); dzz = dzz < -10 ? -10 : (dzz > 10 ? 10 : dzz);
    BZ2[e] = bz[(dzz + 10) * Hc + h];
  }
  bf16x8 qf[8];   // B-frags: B[k=16ks+8hi+i][col=q32]
  {
    const float* qrow = qg + (bhOff + myq) * Dc;
    #pragma unroll
    for (int ks = 0; ks < 4; ++ks) {
      float4 f0 = *(const float4*)(qrow + 16*ks + 8*hi);
      float4 f1 = *(const float4*)(qrow + 16*ks + 8*hi + 4);
      qf[ks] = pack8(sc4(f0, 0.125f), sc4(f1, 0.125f));
    }
    const int qxr = px[b*Sc + myq], qyr = py[b*Sc + myq];
    const short one = (short)0x3F80;
    #pragma unroll
    for (int m = 0; m < 8; ++m) {
      qf[4][m] = (qxr ==      8*hi + m) ? one : (short)0;
      qf[5][m] = (qxr == 16 + 8*hi + m) ? one : (short)0;
      qf[6][m] = (qyr ==      8*hi + m) ? one : (short)0;
      qf[7][m] = (qyr == 16 + 8*hi + m) ? one : (short)0;
    }
  }
  const int qz16 = pz[b*Sc + myq] << 4;

  float mrow = -INFINITY, lsum = 0.0f;
  f32x16 O2[2];
  #pragma unroll
  for (int nt2 = 0; nt2 < 2; ++nt2)
    #pragma unroll
    for (int r = 0; r < 16; ++r) O2[nt2][r] = 0.0f;

  __syncthreads();   // KA[ktb] staged (vmcnt drained), BZ2 visible

  for (int kt = ktb; kt < kte; ++kt) {
    const int cur = (kt - ktb) & 1;
    const int nb  = cur ^ 1;
    const bool pf = (kt + 1 < kte);
    const int k0 = kt * 64;

    // ---- early: KA[kt+1] async; Vt A-frags + kz -> regs
    if (pf) {
      const char* srcK = kaSrc + ((size_t)(bh*1024 + (kt+1)*64)) * 256 + t*16;
      #pragma unroll
      for (int r8 = 0; r8 < 8; ++r8)
        gl16(srcK + r8*2048, (char*)KAb[nb] + r8*2048 + w2*1024);
    }
    bf16x8 vf[2][4];   // A[row=d=32nt2+q32][k=keys 16c4+8hi+i]
    {
      const char* vtile = vtSrc + ((size_t)(bh*16 + kt)) * 8192;
      #pragma unroll
      for (int nt2 = 0; nt2 < 2; ++nt2) {
        const int d = 32*nt2 + q32;
        const char* vrow = vtile + d * 128;
        const int dx = d & 7;
        #pragma unroll
        for (int c4 = 0; c4 < 4; ++c4)
          vf[nt2][c4] = *(const bf16x8*)(vrow + (((2*c4 + hi) ^ dx) << 4));
      }
    }
    int kzv[2][4][4];
    #pragma unroll
    for (int kk = 0; kk < 2; ++kk)
      #pragma unroll
      for (int g = 0; g < 4; ++g) {
        int4 k4 = *(const int4*)(pz + b*Sc + k0 + 32*kk + 8*g + 4*hi);
        kzv[kk][g][0] = k4.x; kzv[kk][g][1] = k4.y;
        kzv[kk][g][2] = k4.z; kzv[kk][g][3] = k4.w;
      }

    // ---- S^T = KA x Q : per kk 8 MFMA_32 (K=128)
    f32x16 s2[2];
    #pragma unroll
    for (int kk = 0; kk < 2; ++kk) {
      #pragma unroll
      for (int r = 0; r < 16; ++r) s2[kk][r] = 0.0f;
      const char* base = (const char*)KAb[cur] + (32*kk + q32) * 256;
      const int rx = q32 & 7;
      #pragma unroll
      for (int ks = 0; ks < 8; ++ks) {
        bf16x8 af = *(const bf16x8*)(base + (((2*ks + hi) ^ rx) << 4));
        s2[kk] = __builtin_amdgcn_mfma_f32_32x32x16_bf16(af, qf[ks], s2[kk], 0, 0, 0);
      }
    }

    // ---- z-bias (+ causal mask on diag tile)
    const bool diag = (kt == qi);
    #pragma unroll
    for (int kk = 0; kk < 2; ++kk) {
      #pragma unroll
      for (int r = 0; r < 16; ++r) {
        float val = s2[kk][r] + BZ2[qz16 | kzv[kk][r>>2][r&3]];
        if (diag) {
          const int key = k0 + 32*kk + (r&3) + 8*(r>>2) + 4*hi;
          if (key > myq) val = -INFINITY;
        }
        s2[kk][r] = val;
      }
    }

    // ---- lane-local online softmax (q = q32 fixed per lane)
    float rmax = s2[0][0];
    #pragma unroll
    for (int kk = 0; kk < 2; ++kk)
      #pragma unroll
      for (int r = 0; r < 16; ++r) rmax = fmaxf(rmax, s2[kk][r]);
    rmax = fmaxf(rmax, __shfl_xor(rmax, 32));
    const float mn = fmaxf(mrow, rmax);
    const float alpha = __expf(mrow - mn);
    mrow = mn;
    float ps = 0.0f;
    #pragma unroll
    for (int kk = 0; kk < 2; ++kk)
      #pragma unroll
      for (int r = 0; r < 16; ++r) {
        const float p = __expf(s2[kk][r] - mn);
        s2[kk][r] = p;
        ps += p;
      }
    ps += __shfl_xor(ps, 32);
    lsum = lsum * alpha + ps;
    #pragma unroll
    for (int nt2 = 0; nt2 < 2; ++nt2)
      #pragma unroll
      for (int r = 0; r < 16; ++r) O2[nt2][r] *= alpha;

    // ---- P -> bf16 B-frags in-register (pack2 + shfl_xor(32) + select)
    // pk[kk][j] packs keys {key(2j), key(2j)+1}; partner (hi^1) holds keys+4.
    unsigned pk[2][8], sw[2][8];
    #pragma unroll
    for (int kk = 0; kk < 2; ++kk)
      #pragma unroll
      for (int jj = 0; jj < 8; ++jj) {
        pk[kk][jj] = pack2(s2[kk][2*jj], s2[kk][2*jj + 1]);
        sw[kk][jj] = __shfl_xor((int)pk[kk][jj], 32);
      }

    // ---- O^T += Vt x P
    #pragma unroll
    for (int kk = 0; kk < 2; ++kk) {
      #pragma unroll
      for (int ks2 = 0; ks2 < 2; ++ks2) {
        union { unsigned u[4]; bf16x8 v; } pf_;
        pf_.u[0] = hi ? sw[kk][4*ks2 + 2] : pk[kk][4*ks2];
        pf_.u[1] = hi ? sw[kk][4*ks2 + 3] : pk[kk][4*ks2 + 1];
        pf_.u[2] = hi ? pk[kk][4*ks2 + 2] : sw[kk][4*ks2];
        pf_.u[3] = hi ? pk[kk][4*ks2 + 3] : sw[kk][4*ks2 + 1];
        const int c4 = 2*kk + ks2;
        #pragma unroll
        for (int nt2 = 0; nt2 < 2; ++nt2)
          O2[nt2] = __builtin_amdgcn_mfma_f32_32x32x16_bf16(vf[nt2][c4], pf_.v, O2[nt2], 0, 0, 0);
      }
    }

    __syncthreads();   // one barrier/step: drains KA[nb] gl16, flips buffers
  }

  // ---- epilogue: lane owns q=myq column; d = 32nt2 + (r&3) + 8*(r>>2) + 4hi
  if (np == 1) {
    const float inv = 1.0f / lsum;
    float* orow = outg + (bhOff + myq) * Dc;
    #pragma unroll
    for (int nt2 = 0; nt2 < 2; ++nt2)
      #pragma unroll
      for (int jq = 0; jq < 4; ++jq) {
        float4 o4 = make_float4(O2[nt2][4*jq]*inv,   O2[nt2][4*jq+1]*inv,
                                O2[nt2][4*jq+2]*inv, O2[nt2][4*jq+3]*inv);
        *(float4*)(orow + 32*nt2 + 8*jq + 4*hi) = o4;
      }
  } else {
    float* rowp = wsPart + ((((size_t)bh * 12 + (qi - 4)) * 3 + part) * 64
                            + 32*w2 + q32) * 68;
    #pragma unroll
    for (int nt2 = 0; nt2 < 2; ++nt2)
      #pragma unroll
      for (int jq = 0; jq < 4; ++jq) {
        float4 o4 = make_float4(O2[nt2][4*jq],   O2[nt2][4*jq+1],
                                O2[nt2][4*jq+2], O2[nt2][4*jq+3]);
        *(float4*)(rowp + 32*nt2 + 8*jq + 4*hi) = o4;
      }
    if (hi == 0) { rowp[64] = mrow; rowp[65] = lsum; }
  }
}

// merge 2-3 partials per (bh, qi>=4) row; partial row pitch 68 (16B-aligned)
__global__ __launch_bounds__(256) void attn_rpb_combine(
    const float* __restrict__ wsPart, float* __restrict__ outg)
{
  const int t = threadIdx.x;
  const int ridx = blockIdx.x * 4 + (t >> 6);
  const int d = t & 63;
  const int bh = ridx / 768;
  const int rem = ridx - bh * 768;
  const int qj = rem >> 6;
  const int rl = rem & 63;
  const float* p0 = wsPart + (((size_t)bh * 12 + qj) * 3 + 0) * 64 * 68 + (size_t)rl * 68;
  const float* p1 = p0 + 64 * 68;
  const float m0 = p0[64], l0 = p0[65];
  const float m1 = p1[64], l1 = p1[65];
  float m = fmaxf(m0, m1);
  float o, lc;
  if (qj >= 8) {
    const float* p2 = p1 + 64 * 68;
    const float m2 = p2[64], l2 = p2[65];
    m = fmaxf(m, m2);
    const float w0 = __expf(m0 - m), w1 = __expf(m1 - m), w2 = __expf(m2 - m);
    lc = l0 * w0 + l1 * w1 + l2 * w2;
    o  = p0[d] * w0 + p1[d] * w1 + p2[d] * w2;
  } else {
    const float w0 = __expf(m0 - m), w1 = __expf(m1 - m);
    lc = l0 * w0 + l1 * w1;
    o  = p0[d] * w0 + p1[d] * w1;
  }
  outg[((size_t)bh * Sc + (qj + 4) * 64 + rl) * Dc + d] = o / lc;
}

extern "C" void kernel_launch(void* const* d_in, const int* in_sizes, int n_in,
                              void* d_out, int out_size, void* d_ws, size_t ws_size,
                              hipStream_t stream) {
  const float* q  = (const float*)d_in[0];
  const float* k  = (const float*)d_in[1];
  const float* v  = (const float*)d_in[2];
  const int*   px = (const int*)d_in[3];
  const int*   py = (const int*)d_in[4];
  const int*   pz = (const int*)d_in[5];
  const float* bx = (const float*)d_in[6];
  const float* by = (const float*)d_in[7];
  const float* bz = (const float*)d_in[8];
  float* out = (float*)d_out;

  unsigned short* wsKA = (unsigned short*)d_ws;
  unsigned short* wsVt = (unsigned short*)((char*)d_ws + KA_BYTES);
  float* wsPart = (float*)((char*)d_ws + PART_OFF);

  prep<<<1024, 256, 0, stream>>>(k, v, px, py, bx, by, wsKA, wsVt);

  if (ws_size >= WS_SPLIT) {
    attn_rpb_mfma9<<<1024, 128, 0, stream>>>(q, px, py, pz, bz, wsKA, wsVt, out, wsPart, 1);
    attn_rpb_combine<<<6144, 256, 0, stream>>>(wsPart, out);
  } else {
    attn_rpb_mfma9<<<512, 128, 0, stream>>>(q, px, py, pz, bz, wsKA, wsVt, out, wsPart, 0);
  }
}